// Round 20
// baseline (196.007 us; speedup 1.0000x reference)
//
#include <hip/hip_runtime.h>
#include <hip/hip_bf16.h>

#define SEQ   2048
#define DH    64
#define KBLK  64
#define NKT   (SEQ / KBLK)   /* 32 */
#define NHEAD 32             /* B*H */
#define TILE_SHORTS (KBLK * DH)        /* 4096 */
#define TILE_BYTES  (TILE_SHORTS * 2)  /* 8192 */
#define LDP   72             /* fallback kernel pad */
#define LDPP  80             /* prep kernel pad */
#define MEXP  20.0f          /* fixed softmax max, log2 domain */

typedef __attribute__((ext_vector_type(8))) short bf16x8;
typedef __attribute__((ext_vector_type(4))) float f32x4;

__device__ __forceinline__ short f2bf(float f) {
    union { float f; unsigned u; } v; v.f = f;
    unsigned r = v.u + 0x7fffu + ((v.u >> 16) & 1u);  // RNE
    return (short)(r >> 16);
}

__device__ __forceinline__ short f2bf_hw(float f) {
    __hip_bfloat16 h = __float2bfloat16(f);
    union { __hip_bfloat16 h; short s; } u; u.h = h;
    return u.s;
}

__device__ __forceinline__ float exp2fast(float x) {
    return __builtin_amdgcn_exp2f(x);
}

// V k-permutation (r11, verified): lane's swapped-QK outputs ARE its PV A-frag.
__device__ __forceinline__ int kperm(int k) {
    return (k & 0x23) | ((k & 0x0C) << 1) | ((k & 0x10) >> 2);
}

// ---------------------------------------------------------------------------
// Pre-pass (r14, verified): K and V -> bf16 FRAGMENT-TILED workspace. Per
// 64x64 tile, 8 chunks of 1KB; chunk c, lane l, shorts j=0..7 hold exactly
// the fragment element lane l consumes:
//   row = (c>>1)*16 + (l&15), off = (c&1)*32 + (l>>4)*8 + j
//   K: K[row = k][off = d]            (chunk c = n*2+d0)
//   V: Vt[row = d][off = kpos]        (chunk c = dt*2+ks, kperm'd)
// -> every main-kernel fragment read is ONE coalesced global_load_dwordx4.
// ---------------------------------------------------------------------------
__global__ __launch_bounds__(256) void prep_kv(const float* __restrict__ Kg,
                                               const float* __restrict__ Vg,
                                               short* __restrict__ wsK,
                                               short* __restrict__ wsV)
{
    __shared__ short Ls[64][LDPP];
    const int t = blockIdx.x, head = blockIdx.y, isV = blockIdx.z;
    const int tid = threadIdx.x;
    const float* src = (isV ? Vg : Kg) + ((size_t)head * SEQ + (size_t)t * KBLK) * DH;
    short* dst = (isV ? wsV : wsK) + ((size_t)head * NKT + t) * TILE_SHORTS;

    #pragma unroll
    for (int it = 0; it < 4; ++it) {
        const int f  = tid + it * 256;
        const int r  = f >> 4;
        const int c4 = (f & 15) * 4;
        const float4 v = *(const float4*)(src + (size_t)r * DH + c4);
        if (!isV) {
            short* p = &Ls[r][c4];
            p[0]=f2bf(v.x); p[1]=f2bf(v.y); p[2]=f2bf(v.z); p[3]=f2bf(v.w);
        } else {
            const int kc = kperm(r);
            Ls[c4+0][kc]=f2bf(v.x); Ls[c4+1][kc]=f2bf(v.y);
            Ls[c4+2][kc]=f2bf(v.z); Ls[c4+3][kc]=f2bf(v.w);
        }
    }
    __syncthreads();
    #pragma unroll
    for (int it = 0; it < 2; ++it) {
        const int s = tid + it * 256;      // 512 bf16x8 slots
        const int c = s >> 6;              // chunk 0..7
        const int l = s & 63;              // lane
        const int row = (c >> 1) * 16 + (l & 15);
        const int off = (c & 1) * 32 + ((l >> 4) * 8);
        const bf16x8 val = *(const bf16x8*)&Ls[row][off];
        *(bf16x8*)(dst + (size_t)s * 8) = val;
    }
}

// ---------------------------------------------------------------------------
// Main kernel — r17 zero-sync structure + SPLIT-K wave pairs:
//  - 256 blocks x 1024 thr (1 block/CU, 16 waves = 4/SIMD). Wave wq (0..7)
//    owns unit u as in r17 (32 q-rows); wave wq+8 is its split-K partner:
//    wq takes tiles [0, nh), wq+8 takes [nh, nt). DIFFERENT tiles -> same
//    L2 traffic as r17, but longest serial chain 32 -> 16 tiles and TLP
//    2 -> 4 waves/SIMD. Free drift (no sync) until ONE final merge barrier.
//  - fixed-max softmax makes the split-K merge a plain sum (exact).
//  - r12 dual-subgroup compute (2:1 frag reuse), swapped QK + kperm V
//    (register P), -MEXP in MFMA C-init, static even/odd reg pipelining.
// ---------------------------------------------------------------------------
__global__ __launch_bounds__(1024, 4) void sdpa_fwd20(const float* __restrict__ Qg,
                                                      const short* __restrict__ wsK,
                                                      const short* __restrict__ wsV,
                                                      float* __restrict__ Og)
{
    __shared__ __align__(16) float mrg[8 * 64 * 36];   // 73728 B merge buffer

    // ---- block -> (head, k4); wave -> (unit u, half) ----
    const int b  = blockIdx.x;                 // 0..255
    const int x  = b & 7;                      // XCD
    const int head = x + 8 * ((b >> 3) & 3);   // 4 heads per XCD
    const int k4 = b >> 5;                     // 0..7

    const int tid  = threadIdx.x;
    const int wave = tid >> 6;                 // 0..15
    const int wq   = wave & 7;                 // unit selector (as r17)
    const int half = wave >> 3;                // split-K half
    const int lane = tid & 63;
    const int lg   = lane >> 4;
    const int lc   = lane & 15;

    const int ulow = k4 * 4 + (wq & 3);
    const int u    = (wq < 4) ? ulow : (63 - ulow);   // 32-row unit 0..63

    const int q0 = u * 32;
    const int nt = (u >> 1) + 1;               // k-tiles for this unit
    const int nh = (nt + 1) >> 1;              // first-half size
    const int t0   = half ? nh : 0;
    const int tend = half ? nt : nh;
    const size_t hbase = (size_t)head * SEQ * DH;

    const char* gK = (const char*)(wsK + (size_t)head * NKT * TILE_SHORTS);
    const char* gV = (const char*)(wsV + (size_t)head * NKT * TILE_SHORTS);
    const int lb = lane * 16;
    const float QSCALE = 0.125f * 1.44269504f;
    const f32x4 minit = (f32x4){-MEXP, -MEXP, -MEXP, -MEXP};

    // ---- Q fragments for both 16-row subgroups ----
    bf16x8 qfA[2], qfB[2];
    #pragma unroll
    for (int gg = 0; gg < 2; ++gg) {
        const int qrow = q0 + gg * 16 + lc;
        #pragma unroll
        for (int d0 = 0; d0 < 2; ++d0) {
            const float* src = Qg + hbase + (size_t)qrow * DH + d0 * 32 + lg * 8;
            const float4 va = ((const float4*)src)[0];
            const float4 vb = ((const float4*)src)[1];
            bf16x8 f;
            f[0]=f2bf(va.x*QSCALE); f[1]=f2bf(va.y*QSCALE);
            f[2]=f2bf(va.z*QSCALE); f[3]=f2bf(va.w*QSCALE);
            f[4]=f2bf(vb.x*QSCALE); f[5]=f2bf(vb.y*QSCALE);
            f[6]=f2bf(vb.z*QSCALE); f[7]=f2bf(vb.w*QSCALE);
            if (gg == 0) qfA[d0] = f; else qfB[d0] = f;
        }
    }

    f32x4 oA[4], oB[4];
    #pragma unroll
    for (int dt = 0; dt < 4; ++dt) {
        oA[dt] = (f32x4){0.f, 0.f, 0.f, 0.f};
        oB[dt] = (f32x4){0.f, 0.f, 0.f, 0.f};
    }
    float lA = 0.f, lB = 0.f;

    bf16x8 kfE[8], vfE[8], kfO[8], vfO[8];

    auto loadT = [&](int t, bf16x8* kf, bf16x8* vf) {
        const char* bK = gK + (size_t)t * TILE_BYTES;
        const char* bV = gV + (size_t)t * TILE_BYTES;
        #pragma unroll
        for (int c = 0; c < 8; ++c) kf[c] = *(const bf16x8*)(bK + c * 1024 + lb);
        #pragma unroll
        for (int c = 0; c < 8; ++c) vf[c] = *(const bf16x8*)(bV + c * 1024 + lb);
    };

    auto body = [&](int t, const bf16x8* kf, const bf16x8* vf) {
        // ---- S^T = K Q^T, one K-frag feeds both subgroups ----
        f32x4 sA[4], sB[4];
        __builtin_amdgcn_s_setprio(1);
        #pragma unroll
        for (int n = 0; n < 4; ++n) {
            f32x4 aA = minit, aB = minit;
            #pragma unroll
            for (int d0 = 0; d0 < 2; ++d0) {
                const bf16x8 kfrag = kf[n*2 + d0];
                aA = __builtin_amdgcn_mfma_f32_16x16x32_bf16(kfrag, qfA[d0], aA, 0, 0, 0);
                aB = __builtin_amdgcn_mfma_f32_16x16x32_bf16(kfrag, qfB[d0], aB, 0, 0, 0);
            }
            sA[n] = aA; sB[n] = aB;
        }
        __builtin_amdgcn_s_setprio(0);

        // ---- causal mask (swapped indices), unit's last tile only ----
        if (t == nt - 1) {
            const int qgA = q0 + lc;
            const int qgB = qgA + 16;
            #pragma unroll
            for (int n = 0; n < 4; ++n) {
                #pragma unroll
                for (int i = 0; i < 4; ++i) {
                    const int kg = t * KBLK + n*16 + lg*4 + i;
                    if (kg > qgA) sA[n][i] = -1e30f;
                    if (kg > qgB) sB[n][i] = -1e30f;
                }
            }
        }

        // ---- fixed-max softmax: P = 2^s ----
        #pragma unroll
        for (int n = 0; n < 4; ++n) {
            #pragma unroll
            for (int i = 0; i < 4; ++i) {
                const float pA = exp2fast(sA[n][i]);
                sA[n][i] = pA; lA += pA;
                const float pB = exp2fast(sB[n][i]);
                sB[n][i] = pB; lB += pB;
            }
        }

        // ---- pack P in-register ----
        bf16x8 paA0, paA1, paB0, paB1;
        #pragma unroll
        for (int i = 0; i < 4; ++i) {
            paA0[i]     = f2bf_hw(sA[0][i]);
            paA0[4 + i] = f2bf_hw(sA[1][i]);
            paA1[i]     = f2bf_hw(sA[2][i]);
            paA1[4 + i] = f2bf_hw(sA[3][i]);
            paB0[i]     = f2bf_hw(sB[0][i]);
            paB0[4 + i] = f2bf_hw(sB[1][i]);
            paB1[i]     = f2bf_hw(sB[2][i]);
            paB1[4 + i] = f2bf_hw(sB[3][i]);
        }

        // ---- O += P V, one V-frag feeds both subgroups ----
        __builtin_amdgcn_s_setprio(1);
        #pragma unroll
        for (int dt = 0; dt < 4; ++dt) {
            const bf16x8 vf0 = vf[dt*2 + 0];
            oA[dt] = __builtin_amdgcn_mfma_f32_16x16x32_bf16(paA0, vf0, oA[dt], 0, 0, 0);
            oB[dt] = __builtin_amdgcn_mfma_f32_16x16x32_bf16(paB0, vf0, oB[dt], 0, 0, 0);
        }
        #pragma unroll
        for (int dt = 0; dt < 4; ++dt) {
            const bf16x8 vf1 = vf[dt*2 + 1];
            oA[dt] = __builtin_amdgcn_mfma_f32_16x16x32_bf16(paA1, vf1, oA[dt], 0, 0, 0);
            oB[dt] = __builtin_amdgcn_mfma_f32_16x16x32_bf16(paB1, vf1, oB[dt], 0, 0, 0);
        }
        __builtin_amdgcn_s_setprio(0);
    };

    // ---- zero-sync pipelined loop over this wave's tile range ----
    if (t0 < tend)     loadT(t0, kfE, vfE);
    if (t0 + 1 < tend) loadT(t0 + 1, kfO, vfO);
    for (int tt = t0; tt < tend; tt += 2) {
        body(tt, kfE, vfE);
        if (tt + 2 < tend) loadT(tt + 2, kfE, vfE);
        if (tt + 1 < tend) {
            body(tt + 1, kfO, vfO);
            if (tt + 3 < tend) loadT(tt + 3, kfO, vfO);
        }
    }

    // ---- ONE merge barrier: half-1 partials -> LDS -> half-0 adds ----
    __syncthreads();
    if (half == 1) {
        float* bse = mrg + (size_t)(wq * 64 + lane) * 36;
        #pragma unroll
        for (int dt = 0; dt < 4; ++dt) {
            *(f32x4*)(bse + dt * 4)      = oA[dt];
            *(f32x4*)(bse + 16 + dt * 4) = oB[dt];
        }
        bse[32] = lA; bse[33] = lB;
    }
    __syncthreads();
    if (half == 0) {
        const float* bse = mrg + (size_t)(wq * 64 + lane) * 36;
        #pragma unroll
        for (int dt = 0; dt < 4; ++dt) {
            oA[dt] += *(const f32x4*)(bse + dt * 4);
            oB[dt] += *(const f32x4*)(bse + 16 + dt * 4);
        }
        lA += bse[32]; lB += bse[33];

        // ---- epilogue: reduce l across lg, shfl-transpose, store ----
        #pragma unroll
        for (int gg = 0; gg < 2; ++gg) {
            float l = (gg == 0) ? lA : lB;
            l += __shfl_xor(l, 16);
            l += __shfl_xor(l, 32);
            const float inv = 1.f / l;
            #pragma unroll
            for (int i = 0; i < 4; ++i) {
                const int q = lg*4 + i;
                const float invq = __shfl(inv, (lane & 48) | q);
                const int qg = q0 + gg*16 + q;
                float* dst = Og + hbase + (size_t)qg * DH;
                #pragma unroll
                for (int dt = 0; dt < 4; ++dt)
                    dst[dt*16 + lc] = ((gg == 0) ? oA[dt][i] : oB[dt][i]) * invq;
            }
        }
    }
}

// ---------------------------------------------------------------------------
// Fallback (round-1 kernel) if workspace is too small.
// ---------------------------------------------------------------------------
__global__ __launch_bounds__(256) void sdpa_fwd_fb(const float* __restrict__ Qg,
                                                   const float* __restrict__ Kg,
                                                   const float* __restrict__ Vg,
                                                   float* __restrict__ Og)
{
    __shared__ __align__(16) short Kt[KBLK][LDP];
    __shared__ __align__(16) short Vt[DH][LDP];
    __shared__ __align__(16) short Pt[4][16][LDP];

    const int head = blockIdx.y;
    const int qb   = 31 - blockIdx.x;
    const int tid  = threadIdx.x;
    const int wave = tid >> 6;
    const int lane = tid & 63;
    const int lg   = lane >> 4;
    const int lc   = lane & 15;

    const int q0 = qb * 64;
    const size_t hbase = (size_t)head * SEQ * DH;

    bf16x8 qfrag[2];
    {
        const int qrow = q0 + wave * 16 + lc;
        #pragma unroll
        for (int d0 = 0; d0 < 2; ++d0) {
            const float* src = Qg + hbase + (size_t)qrow * DH + d0 * 32 + lg * 8;
            const float4 va = ((const float4*)src)[0];
            const float4 vb = ((const float4*)src)[1];
            bf16x8 f;
            f[0]=f2bf(va.x*0.125f); f[1]=f2bf(va.y*0.125f);
            f[2]=f2bf(va.z*0.125f); f[3]=f2bf(va.w*0.125f);
            f[4]=f2bf(vb.x*0.125f); f[5]=f2bf(vb.y*0.125f);
            f[6]=f2bf(vb.z*0.125f); f[7]=f2bf(vb.w*0.125f);
            qfrag[d0] = f;
        }
    }

    f32x4 o_acc[4];
    #pragma unroll
    for (int dt = 0; dt < 4; ++dt) o_acc[dt] = (f32x4){0.f, 0.f, 0.f, 0.f};
    float m_run[4], l_run[4];
    #pragma unroll
    for (int i = 0; i < 4; ++i) { m_run[i] = -1e30f; l_run[i] = 0.f; }

    const int ntiles = qb + 1;
    for (int kt = 0; kt < ntiles; ++kt) {
        const int k0 = kt * KBLK;
        __syncthreads();
        #pragma unroll
        for (int it = 0; it < 4; ++it) {
            const int f  = tid + it * 256;
            const int kr = f >> 4;
            const int c4 = (f & 15) * 4;
            const float4 kv = *(const float4*)(Kg + hbase + (size_t)(k0 + kr) * DH + c4);
            short* kd = &Kt[kr][c4];
            kd[0]=f2bf(kv.x); kd[1]=f2bf(kv.y); kd[2]=f2bf(kv.z); kd[3]=f2bf(kv.w);
            const float4 vv = *(const float4*)(Vg + hbase + (size_t)(k0 + kr) * DH + c4);
            Vt[c4+0][kr]=f2bf(vv.x); Vt[c4+1][kr]=f2bf(vv.y);
            Vt[c4+2][kr]=f2bf(vv.z); Vt[c4+3][kr]=f2bf(vv.w);
        }
        __syncthreads();

        f32x4 s_acc[4];
        #pragma unroll
        for (int n = 0; n < 4; ++n) {
            f32x4 acc = {0.f, 0.f, 0.f, 0.f};
            #pragma unroll
            for (int d0 = 0; d0 < 2; ++d0) {
                const bf16x8 bfrag = *(const bf16x8*)&Kt[n*16 + lc][d0*32 + lg*8];
                acc = __builtin_amdgcn_mfma_f32_16x16x32_bf16(qfrag[d0], bfrag, acc, 0, 0, 0);
            }
            s_acc[n] = acc;
        }

        const int qrow_g = q0 + wave * 16 + lg * 4;
        if (kt == ntiles - 1) {
            #pragma unroll
            for (int i = 0; i < 4; ++i) {
                const int qg = qrow_g + i;
                #pragma unroll
                for (int n = 0; n < 4; ++n) {
                    const int kg = k0 + n*16 + lc;
                    if (kg > qg) s_acc[n][i] = -1e30f;
                }
            }
        }

        #pragma unroll
        for (int i = 0; i < 4; ++i) {
            float mx = fmaxf(fmaxf(s_acc[0][i], s_acc[1][i]),
                             fmaxf(s_acc[2][i], s_acc[3][i]));
            mx = fmaxf(mx, __shfl_xor(mx, 1));
            mx = fmaxf(mx, __shfl_xor(mx, 2));
            mx = fmaxf(mx, __shfl_xor(mx, 4));
            mx = fmaxf(mx, __shfl_xor(mx, 8));
            const float m_new = fmaxf(m_run[i], mx);
            const float corr = __expf(m_run[i] - m_new);
            m_run[i] = m_new;
            float rs = 0.f;
            #pragma unroll
            for (int n = 0; n < 4; ++n) {
                const float pp = __expf(s_acc[n][i] - m_new);
                s_acc[n][i] = pp;
                rs += pp;
            }
            rs += __shfl_xor(rs, 1);
            rs += __shfl_xor(rs, 2);
            rs += __shfl_xor(rs, 4);
            rs += __shfl_xor(rs, 8);
            l_run[i] = l_run[i] * corr + rs;
            #pragma unroll
            for (int dt = 0; dt < 4; ++dt) o_acc[dt][i] *= corr;
        }

        #pragma unroll
        for (int n = 0; n < 4; ++n) {
            #pragma unroll
            for (int i = 0; i < 4; ++i)
                Pt[wave][lg*4 + i][n*16 + lc] = f2bf(s_acc[n][i]);
        }
        asm volatile("s_waitcnt lgkmcnt(0)" ::: "memory");

        #pragma unroll
        for (int ks = 0; ks < 2; ++ks) {
            const bf16x8 afrag = *(const bf16x8*)&Pt[wave][lc][ks*32 + lg*8];
            #pragma unroll
            for (int dt = 0; dt < 4; ++dt) {
                const bf16x8 bfrag = *(const bf16x8*)&Vt[dt*16 + lc][ks*32 + lg*8];
                o_acc[dt] = __builtin_amdgcn_mfma_f32_16x16x32_bf16(afrag, bfrag, o_acc[dt], 0, 0, 0);
            }
        }
    }

    #pragma unroll
    for (int i = 0; i < 4; ++i) {
        const float inv = 1.f / l_run[i];
        const int qg = q0 + wave*16 + lg*4 + i;
        float* dst = Og + hbase + (size_t)qg * DH;
        #pragma unroll
        for (int dt = 0; dt < 4; ++dt)
            dst[dt*16 + lc] = o_acc[dt][i] * inv;
    }
}

extern "C" void kernel_launch(void* const* d_in, const int* in_sizes, int n_in,
                              void* d_out, int out_size, void* d_ws, size_t ws_size,
                              hipStream_t stream) {
    const float* Q = (const float*)d_in[0];
    const float* K = (const float*)d_in[1];
    const float* V = (const float*)d_in[2];
    float* O = (float*)d_out;
    const size_t need = (size_t)2 * NHEAD * SEQ * DH * sizeof(short);  // 16 MB
    if (ws_size >= need) {
        short* wsK = (short*)d_ws;
        short* wsV = wsK + (size_t)NHEAD * SEQ * DH;
        prep_kv<<<dim3(NKT, NHEAD, 2), 256, 0, stream>>>(K, V, wsK, wsV);
        sdpa_fwd20<<<dim3(256), 1024, 0, stream>>>(Q, wsK, wsV, O);
    } else {
        sdpa_fwd_fb<<<dim3(32, NHEAD), 256, 0, stream>>>(Q, K, V, O);
    }
}

// Round 21
// 195.460 us; speedup vs baseline: 1.0028x; 1.0028x over previous
//
#include <hip/hip_runtime.h>
#include <hip/hip_bf16.h>

#define SEQ   2048
#define DH    64
#define KBLK  64
#define NKT   (SEQ / KBLK)   /* 32 */
#define NHEAD 32             /* B*H */
#define TILE_SHORTS (KBLK * DH)        /* 4096 */
#define TILE_BYTES  (TILE_SHORTS * 2)  /* 8192 */
#define LDP   72             /* fallback kernel pad */
#define LDPP  80             /* prep kernel pad */
#define MEXP  20.0f          /* fixed softmax max, log2 domain */

typedef __attribute__((ext_vector_type(8))) short bf16x8;
typedef __attribute__((ext_vector_type(4))) float f32x4;

__device__ __forceinline__ short f2bf(float f) {
    union { float f; unsigned u; } v; v.f = f;
    unsigned r = v.u + 0x7fffu + ((v.u >> 16) & 1u);  // RNE
    return (short)(r >> 16);
}

__device__ __forceinline__ short f2bf_hw(float f) {
    __hip_bfloat16 h = __float2bfloat16(f);
    union { __hip_bfloat16 h; short s; } u; u.h = h;
    return u.s;
}

__device__ __forceinline__ float exp2fast(float x) {
    return __builtin_amdgcn_exp2f(x);
}

// V k-permutation (r11, verified): lane's swapped-QK outputs ARE its PV A-frag.
__device__ __forceinline__ int kperm(int k) {
    return (k & 0x23) | ((k & 0x0C) << 1) | ((k & 0x10) >> 2);
}

// ---------------------------------------------------------------------------
// Pre-pass (r14, verified): K and V -> bf16 FRAGMENT-TILED workspace. Per
// 64x64 tile, 8 chunks of 1KB; chunk c, lane l, shorts j=0..7 hold exactly
// the fragment element lane l consumes:
//   row = (c>>1)*16 + (l&15), off = (c&1)*32 + (l>>4)*8 + j
//   K: K[row = k][off = d]            (chunk c = n*2+d0)
//   V: Vt[row = d][off = kpos]        (chunk c = dt*2+ks, kperm'd)
// -> every main-kernel fragment read is ONE coalesced global_load_dwordx4.
// ---------------------------------------------------------------------------
__global__ __launch_bounds__(256) void prep_kv(const float* __restrict__ Kg,
                                               const float* __restrict__ Vg,
                                               short* __restrict__ wsK,
                                               short* __restrict__ wsV)
{
    __shared__ short Ls[64][LDPP];
    const int t = blockIdx.x, head = blockIdx.y, isV = blockIdx.z;
    const int tid = threadIdx.x;
    const float* src = (isV ? Vg : Kg) + ((size_t)head * SEQ + (size_t)t * KBLK) * DH;
    short* dst = (isV ? wsV : wsK) + ((size_t)head * NKT + t) * TILE_SHORTS;

    #pragma unroll
    for (int it = 0; it < 4; ++it) {
        const int f  = tid + it * 256;
        const int r  = f >> 4;
        const int c4 = (f & 15) * 4;
        const float4 v = *(const float4*)(src + (size_t)r * DH + c4);
        if (!isV) {
            short* p = &Ls[r][c4];
            p[0]=f2bf(v.x); p[1]=f2bf(v.y); p[2]=f2bf(v.z); p[3]=f2bf(v.w);
        } else {
            const int kc = kperm(r);
            Ls[c4+0][kc]=f2bf(v.x); Ls[c4+1][kc]=f2bf(v.y);
            Ls[c4+2][kc]=f2bf(v.z); Ls[c4+3][kc]=f2bf(v.w);
        }
    }
    __syncthreads();
    #pragma unroll
    for (int it = 0; it < 2; ++it) {
        const int s = tid + it * 256;      // 512 bf16x8 slots
        const int c = s >> 6;              // chunk 0..7
        const int l = s & 63;              // lane
        const int row = (c >> 1) * 16 + (l & 15);
        const int off = (c & 1) * 32 + ((l >> 4) * 8);
        const bf16x8 val = *(const bf16x8*)&Ls[row][off];
        *(bf16x8*)(dst + (size_t)s * 8) = val;
    }
}

// ---------------------------------------------------------------------------
// Main kernel — r17 zero-sync structure + SPLIT-K wave pairs:
//  - 256 blocks x 1024 thr (1 block/CU, 16 waves = 4/SIMD). Wave wq (0..7)
//    owns unit u as in r17 (32 q-rows); wave wq+8 is its split-K partner:
//    wq takes tiles [0, nh), wq+8 takes [nh, nt). DIFFERENT tiles -> same
//    L2 traffic as r17, but longest serial chain 32 -> 16 tiles and TLP
//    2 -> 4 waves/SIMD. Free drift (no sync) until ONE final merge barrier.
//  - fixed-max softmax makes the split-K merge a plain sum (exact).
//  - r12 dual-subgroup compute (2:1 frag reuse), swapped QK + kperm V
//    (register P), -MEXP in MFMA C-init, static even/odd reg pipelining.
// ---------------------------------------------------------------------------
__global__ __launch_bounds__(1024, 4) void sdpa_fwd20(const float* __restrict__ Qg,
                                                      const short* __restrict__ wsK,
                                                      const short* __restrict__ wsV,
                                                      float* __restrict__ Og)
{
    __shared__ __align__(16) float mrg[8 * 64 * 36];   // 73728 B merge buffer

    // ---- block -> (head, k4); wave -> (unit u, half) ----
    const int b  = blockIdx.x;                 // 0..255
    const int x  = b & 7;                      // XCD
    const int head = x + 8 * ((b >> 3) & 3);   // 4 heads per XCD
    const int k4 = b >> 5;                     // 0..7

    const int tid  = threadIdx.x;
    const int wave = tid >> 6;                 // 0..15
    const int wq   = wave & 7;                 // unit selector (as r17)
    const int half = wave >> 3;                // split-K half
    const int lane = tid & 63;
    const int lg   = lane >> 4;
    const int lc   = lane & 15;

    const int ulow = k4 * 4 + (wq & 3);
    const int u    = (wq < 4) ? ulow : (63 - ulow);   // 32-row unit 0..63

    const int q0 = u * 32;
    const int nt = (u >> 1) + 1;               // k-tiles for this unit
    const int nh = (nt + 1) >> 1;              // first-half size
    const int t0   = half ? nh : 0;
    const int tend = half ? nt : nh;
    const size_t hbase = (size_t)head * SEQ * DH;

    const char* gK = (const char*)(wsK + (size_t)head * NKT * TILE_SHORTS);
    const char* gV = (const char*)(wsV + (size_t)head * NKT * TILE_SHORTS);
    const int lb = lane * 16;
    const float QSCALE = 0.125f * 1.44269504f;
    const f32x4 minit = (f32x4){-MEXP, -MEXP, -MEXP, -MEXP};

    // ---- Q fragments for both 16-row subgroups ----
    bf16x8 qfA[2], qfB[2];
    #pragma unroll
    for (int gg = 0; gg < 2; ++gg) {
        const int qrow = q0 + gg * 16 + lc;
        #pragma unroll
        for (int d0 = 0; d0 < 2; ++d0) {
            const float* src = Qg + hbase + (size_t)qrow * DH + d0 * 32 + lg * 8;
            const float4 va = ((const float4*)src)[0];
            const float4 vb = ((const float4*)src)[1];
            bf16x8 f;
            f[0]=f2bf(va.x*QSCALE); f[1]=f2bf(va.y*QSCALE);
            f[2]=f2bf(va.z*QSCALE); f[3]=f2bf(va.w*QSCALE);
            f[4]=f2bf(vb.x*QSCALE); f[5]=f2bf(vb.y*QSCALE);
            f[6]=f2bf(vb.z*QSCALE); f[7]=f2bf(vb.w*QSCALE);
            if (gg == 0) qfA[d0] = f; else qfB[d0] = f;
        }
    }

    f32x4 oA[4], oB[4];
    #pragma unroll
    for (int dt = 0; dt < 4; ++dt) {
        oA[dt] = (f32x4){0.f, 0.f, 0.f, 0.f};
        oB[dt] = (f32x4){0.f, 0.f, 0.f, 0.f};
    }
    float lA = 0.f, lB = 0.f;

    bf16x8 kfE[8], vfE[8], kfO[8], vfO[8];

    auto loadT = [&](int t, bf16x8* kf, bf16x8* vf) {
        const char* bK = gK + (size_t)t * TILE_BYTES;
        const char* bV = gV + (size_t)t * TILE_BYTES;
        #pragma unroll
        for (int c = 0; c < 8; ++c) kf[c] = *(const bf16x8*)(bK + c * 1024 + lb);
        #pragma unroll
        for (int c = 0; c < 8; ++c) vf[c] = *(const bf16x8*)(bV + c * 1024 + lb);
    };

    auto body = [&](int t, const bf16x8* kf, const bf16x8* vf) {
        // ---- S^T = K Q^T, one K-frag feeds both subgroups ----
        f32x4 sA[4], sB[4];
        __builtin_amdgcn_s_setprio(1);
        #pragma unroll
        for (int n = 0; n < 4; ++n) {
            f32x4 aA = minit, aB = minit;
            #pragma unroll
            for (int d0 = 0; d0 < 2; ++d0) {
                const bf16x8 kfrag = kf[n*2 + d0];
                aA = __builtin_amdgcn_mfma_f32_16x16x32_bf16(kfrag, qfA[d0], aA, 0, 0, 0);
                aB = __builtin_amdgcn_mfma_f32_16x16x32_bf16(kfrag, qfB[d0], aB, 0, 0, 0);
            }
            sA[n] = aA; sB[n] = aB;
        }
        __builtin_amdgcn_s_setprio(0);

        // ---- causal mask (swapped indices), unit's last tile only ----
        if (t == nt - 1) {
            const int qgA = q0 + lc;
            const int qgB = qgA + 16;
            #pragma unroll
            for (int n = 0; n < 4; ++n) {
                #pragma unroll
                for (int i = 0; i < 4; ++i) {
                    const int kg = t * KBLK + n*16 + lg*4 + i;
                    if (kg > qgA) sA[n][i] = -1e30f;
                    if (kg > qgB) sB[n][i] = -1e30f;
                }
            }
        }

        // ---- fixed-max softmax: P = 2^s ----
        #pragma unroll
        for (int n = 0; n < 4; ++n) {
            #pragma unroll
            for (int i = 0; i < 4; ++i) {
                const float pA = exp2fast(sA[n][i]);
                sA[n][i] = pA; lA += pA;
                const float pB = exp2fast(sB[n][i]);
                sB[n][i] = pB; lB += pB;
            }
        }

        // ---- pack P in-register ----
        bf16x8 paA0, paA1, paB0, paB1;
        #pragma unroll
        for (int i = 0; i < 4; ++i) {
            paA0[i]     = f2bf_hw(sA[0][i]);
            paA0[4 + i] = f2bf_hw(sA[1][i]);
            paA1[i]     = f2bf_hw(sA[2][i]);
            paA1[4 + i] = f2bf_hw(sA[3][i]);
            paB0[i]     = f2bf_hw(sB[0][i]);
            paB0[4 + i] = f2bf_hw(sB[1][i]);
            paB1[i]     = f2bf_hw(sB[2][i]);
            paB1[4 + i] = f2bf_hw(sB[3][i]);
        }

        // ---- O += P V, one V-frag feeds both subgroups ----
        __builtin_amdgcn_s_setprio(1);
        #pragma unroll
        for (int dt = 0; dt < 4; ++dt) {
            const bf16x8 vf0 = vf[dt*2 + 0];
            oA[dt] = __builtin_amdgcn_mfma_f32_16x16x32_bf16(paA0, vf0, oA[dt], 0, 0, 0);
            oB[dt] = __builtin_amdgcn_mfma_f32_16x16x32_bf16(paB0, vf0, oB[dt], 0, 0, 0);
        }
        #pragma unroll
        for (int dt = 0; dt < 4; ++dt) {
            const bf16x8 vf1 = vf[dt*2 + 1];
            oA[dt] = __builtin_amdgcn_mfma_f32_16x16x32_bf16(paA1, vf1, oA[dt], 0, 0, 0);
            oB[dt] = __builtin_amdgcn_mfma_f32_16x16x32_bf16(paB1, vf1, oB[dt], 0, 0, 0);
        }
        __builtin_amdgcn_s_setprio(0);
    };

    // ---- zero-sync pipelined loop over this wave's tile range ----
    if (t0 < tend)     loadT(t0, kfE, vfE);
    if (t0 + 1 < tend) loadT(t0 + 1, kfO, vfO);
    for (int tt = t0; tt < tend; tt += 2) {
        body(tt, kfE, vfE);
        if (tt + 2 < tend) loadT(tt + 2, kfE, vfE);
        if (tt + 1 < tend) {
            body(tt + 1, kfO, vfO);
            if (tt + 3 < tend) loadT(tt + 3, kfO, vfO);
        }
    }

    // ---- ONE merge barrier: half-1 partials -> LDS -> half-0 adds ----
    __syncthreads();
    if (half == 1) {
        float* bse = mrg + (size_t)(wq * 64 + lane) * 36;
        #pragma unroll
        for (int dt = 0; dt < 4; ++dt) {
            *(f32x4*)(bse + dt * 4)      = oA[dt];
            *(f32x4*)(bse + 16 + dt * 4) = oB[dt];
        }
        bse[32] = lA; bse[33] = lB;
    }
    __syncthreads();
    if (half == 0) {
        const float* bse = mrg + (size_t)(wq * 64 + lane) * 36;
        #pragma unroll
        for (int dt = 0; dt < 4; ++dt) {
            oA[dt] += *(const f32x4*)(bse + dt * 4);
            oB[dt] += *(const f32x4*)(bse + 16 + dt * 4);
        }
        lA += bse[32]; lB += bse[33];

        // ---- epilogue: reduce l across lg, shfl-transpose, store ----
        #pragma unroll
        for (int gg = 0; gg < 2; ++gg) {
            float l = (gg == 0) ? lA : lB;
            l += __shfl_xor(l, 16);
            l += __shfl_xor(l, 32);
            const float inv = 1.f / l;
            #pragma unroll
            for (int i = 0; i < 4; ++i) {
                const int q = lg*4 + i;
                const float invq = __shfl(inv, (lane & 48) | q);
                const int qg = q0 + gg*16 + q;
                float* dst = Og + hbase + (size_t)qg * DH;
                #pragma unroll
                for (int dt = 0; dt < 4; ++dt)
                    dst[dt*16 + lc] = ((gg == 0) ? oA[dt][i] : oB[dt][i]) * invq;
            }
        }
    }
}

// ---------------------------------------------------------------------------
// Fallback (round-1 kernel) if workspace is too small.
// ---------------------------------------------------------------------------
__global__ __launch_bounds__(256) void sdpa_fwd_fb(const float* __restrict__ Qg,
                                                   const float* __restrict__ Kg,
                                                   const float* __restrict__ Vg,
                                                   float* __restrict__ Og)
{
    __shared__ __align__(16) short Kt[KBLK][LDP];
    __shared__ __align__(16) short Vt[DH][LDP];
    __shared__ __align__(16) short Pt[4][16][LDP];

    const int head = blockIdx.y;
    const int qb   = 31 - blockIdx.x;
    const int tid  = threadIdx.x;
    const int wave = tid >> 6;
    const int lane = tid & 63;
    const int lg   = lane >> 4;
    const int lc   = lane & 15;

    const int q0 = qb * 64;
    const size_t hbase = (size_t)head * SEQ * DH;

    bf16x8 qfrag[2];
    {
        const int qrow = q0 + wave * 16 + lc;
        #pragma unroll
        for (int d0 = 0; d0 < 2; ++d0) {
            const float* src = Qg + hbase + (size_t)qrow * DH + d0 * 32 + lg * 8;
            const float4 va = ((const float4*)src)[0];
            const float4 vb = ((const float4*)src)[1];
            bf16x8 f;
            f[0]=f2bf(va.x*0.125f); f[1]=f2bf(va.y*0.125f);
            f[2]=f2bf(va.z*0.125f); f[3]=f2bf(va.w*0.125f);
            f[4]=f2bf(vb.x*0.125f); f[5]=f2bf(vb.y*0.125f);
            f[6]=f2bf(vb.z*0.125f); f[7]=f2bf(vb.w*0.125f);
            qfrag[d0] = f;
        }
    }

    f32x4 o_acc[4];
    #pragma unroll
    for (int dt = 0; dt < 4; ++dt) o_acc[dt] = (f32x4){0.f, 0.f, 0.f, 0.f};
    float m_run[4], l_run[4];
    #pragma unroll
    for (int i = 0; i < 4; ++i) { m_run[i] = -1e30f; l_run[i] = 0.f; }

    const int ntiles = qb + 1;
    for (int kt = 0; kt < ntiles; ++kt) {
        const int k0 = kt * KBLK;
        __syncthreads();
        #pragma unroll
        for (int it = 0; it < 4; ++it) {
            const int f  = tid + it * 256;
            const int kr = f >> 4;
            const int c4 = (f & 15) * 4;
            const float4 kv = *(const float4*)(Kg + hbase + (size_t)(k0 + kr) * DH + c4);
            short* kd = &Kt[kr][c4];
            kd[0]=f2bf(kv.x); kd[1]=f2bf(kv.y); kd[2]=f2bf(kv.z); kd[3]=f2bf(kv.w);
            const float4 vv = *(const float4*)(Vg + hbase + (size_t)(k0 + kr) * DH + c4);
            Vt[c4+0][kr]=f2bf(vv.x); Vt[c4+1][kr]=f2bf(vv.y);
            Vt[c4+2][kr]=f2bf(vv.z); Vt[c4+3][kr]=f2bf(vv.w);
        }
        __syncthreads();

        f32x4 s_acc[4];
        #pragma unroll
        for (int n = 0; n < 4; ++n) {
            f32x4 acc = {0.f, 0.f, 0.f, 0.f};
            #pragma unroll
            for (int d0 = 0; d0 < 2; ++d0) {
                const bf16x8 bfrag = *(const bf16x8*)&Kt[n*16 + lc][d0*32 + lg*8];
                acc = __builtin_amdgcn_mfma_f32_16x16x32_bf16(qfrag[d0], bfrag, acc, 0, 0, 0);
            }
            s_acc[n] = acc;
        }

        const int qrow_g = q0 + wave * 16 + lg * 4;
        if (kt == ntiles - 1) {
            #pragma unroll
            for (int i = 0; i < 4; ++i) {
                const int qg = qrow_g + i;
                #pragma unroll
                for (int n = 0; n < 4; ++n) {
                    const int kg = k0 + n*16 + lc;
                    if (kg > qg) s_acc[n][i] = -1e30f;
                }
            }
        }

        #pragma unroll
        for (int i = 0; i < 4; ++i) {
            float mx = fmaxf(fmaxf(s_acc[0][i], s_acc[1][i]),
                             fmaxf(s_acc[2][i], s_acc[3][i]));
            mx = fmaxf(mx, __shfl_xor(mx, 1));
            mx = fmaxf(mx, __shfl_xor(mx, 2));
            mx = fmaxf(mx, __shfl_xor(mx, 4));
            mx = fmaxf(mx, __shfl_xor(mx, 8));
            const float m_new = fmaxf(m_run[i], mx);
            const float corr = __expf(m_run[i] - m_new);
            m_run[i] = m_new;
            float rs = 0.f;
            #pragma unroll
            for (int n = 0; n < 4; ++n) {
                const float pp = __expf(s_acc[n][i] - m_new);
                s_acc[n][i] = pp;
                rs += pp;
            }
            rs += __shfl_xor(rs, 1);
            rs += __shfl_xor(rs, 2);
            rs += __shfl_xor(rs, 4);
            rs += __shfl_xor(rs, 8);
            l_run[i] = l_run[i] * corr + rs;
            #pragma unroll
            for (int dt = 0; dt < 4; ++dt) o_acc[dt][i] *= corr;
        }

        #pragma unroll
        for (int n = 0; n < 4; ++n) {
            #pragma unroll
            for (int i = 0; i < 4; ++i)
                Pt[wave][lg*4 + i][n*16 + lc] = f2bf(s_acc[n][i]);
        }
        asm volatile("s_waitcnt lgkmcnt(0)" ::: "memory");

        #pragma unroll
        for (int ks = 0; ks < 2; ++ks) {
            const bf16x8 afrag = *(const bf16x8*)&Pt[wave][lc][ks*32 + lg*8];
            #pragma unroll
            for (int dt = 0; dt < 4; ++dt) {
                const bf16x8 bfrag = *(const bf16x8*)&Vt[dt*16 + lc][ks*32 + lg*8];
                o_acc[dt] = __builtin_amdgcn_mfma_f32_16x16x32_bf16(afrag, bfrag, o_acc[dt], 0, 0, 0);
            }
        }
    }

    #pragma unroll
    for (int i = 0; i < 4; ++i) {
        const float inv = 1.f / l_run[i];
        const int qg = q0 + wave*16 + lg*4 + i;
        float* dst = Og + hbase + (size_t)qg * DH;
        #pragma unroll
        for (int dt = 0; dt < 4; ++dt)
            dst[dt*16 + lc] = o_acc[dt][i] * inv;
    }
}

extern "C" void kernel_launch(void* const* d_in, const int* in_sizes, int n_in,
                              void* d_out, int out_size, void* d_ws, size_t ws_size,
                              hipStream_t stream) {
    const float* Q = (const float*)d_in[0];
    const float* K = (const float*)d_in[1];
    const float* V = (const float*)d_in[2];
    float* O = (float*)d_out;
    const size_t need = (size_t)2 * NHEAD * SEQ * DH * sizeof(short);  // 16 MB
    if (ws_size >= need) {
        short* wsK = (short*)d_ws;
        short* wsV = wsK + (size_t)NHEAD * SEQ * DH;
        prep_kv<<<dim3(NKT, NHEAD, 2), 256, 0, stream>>>(K, V, wsK, wsV);
        sdpa_fwd20<<<dim3(256), 1024, 0, stream>>>(Q, wsK, wsV, O);
    } else {
        sdpa_fwd_fb<<<dim3(32, NHEAD), 256, 0, stream>>>(Q, K, V, O);
    }
}

// Round 22
// 41.732 us; speedup vs baseline: 4.6968x; 4.6837x over previous
//
#include <hip/hip_runtime.h>
#include <hip/hip_bf16.h>

#define SEQ   2048
#define DH    64
#define KBLK  64
#define NKT   (SEQ / KBLK)   /* 32 */
#define NHEAD 32             /* B*H */
#define TILE_SHORTS (KBLK * DH)        /* 4096 */
#define TILE_BYTES  (TILE_SHORTS * 2)  /* 8192 */
#define LDP   72             /* fallback kernel pad */
#define LDPP  80             /* prep kernel pad */
#define MEXP  20.0f          /* fixed softmax max, log2 domain */

typedef __attribute__((ext_vector_type(8))) short bf16x8;
typedef __attribute__((ext_vector_type(4))) float f32x4;

__device__ __forceinline__ short f2bf(float f) {
    union { float f; unsigned u; } v; v.f = f;
    unsigned r = v.u + 0x7fffu + ((v.u >> 16) & 1u);  // RNE
    return (short)(r >> 16);
}

__device__ __forceinline__ short f2bf_hw(float f) {
    __hip_bfloat16 h = __float2bfloat16(f);
    union { __hip_bfloat16 h; short s; } u; u.h = h;
    return u.s;
}

__device__ __forceinline__ float exp2fast(float x) {
    return __builtin_amdgcn_exp2f(x);
}

// V k-permutation (r11, verified): lane's swapped-QK outputs ARE its PV A-frag.
__device__ __forceinline__ int kperm(int k) {
    return (k & 0x23) | ((k & 0x0C) << 1) | ((k & 0x10) >> 2);
}

// ---------------------------------------------------------------------------
// Pre-pass (r14, verified): K and V -> bf16 FRAGMENT-TILED workspace. Per
// 64x64 tile, 8 chunks of 1KB; chunk c, lane l, shorts j=0..7 hold exactly
// the fragment element lane l consumes:
//   row = (c>>1)*16 + (l&15), off = (c&1)*32 + (l>>4)*8 + j
//   K: K[row = k][off = d]            (chunk c = n*2+d0)
//   V: Vt[row = d][off = kpos]        (chunk c = dt*2+ks, kperm'd)
// -> every main-kernel fragment read is ONE coalesced global_load_dwordx4.
// ---------------------------------------------------------------------------
__global__ __launch_bounds__(256) void prep_kv(const float* __restrict__ Kg,
                                               const float* __restrict__ Vg,
                                               short* __restrict__ wsK,
                                               short* __restrict__ wsV)
{
    __shared__ short Ls[64][LDPP];
    const int t = blockIdx.x, head = blockIdx.y, isV = blockIdx.z;
    const int tid = threadIdx.x;
    const float* src = (isV ? Vg : Kg) + ((size_t)head * SEQ + (size_t)t * KBLK) * DH;
    short* dst = (isV ? wsV : wsK) + ((size_t)head * NKT + t) * TILE_SHORTS;

    #pragma unroll
    for (int it = 0; it < 4; ++it) {
        const int f  = tid + it * 256;
        const int r  = f >> 4;
        const int c4 = (f & 15) * 4;
        const float4 v = *(const float4*)(src + (size_t)r * DH + c4);
        if (!isV) {
            short* p = &Ls[r][c4];
            p[0]=f2bf(v.x); p[1]=f2bf(v.y); p[2]=f2bf(v.z); p[3]=f2bf(v.w);
        } else {
            const int kc = kperm(r);
            Ls[c4+0][kc]=f2bf(v.x); Ls[c4+1][kc]=f2bf(v.y);
            Ls[c4+2][kc]=f2bf(v.z); Ls[c4+3][kc]=f2bf(v.w);
        }
    }
    __syncthreads();
    #pragma unroll
    for (int it = 0; it < 2; ++it) {
        const int s = tid + it * 256;      // 512 bf16x8 slots
        const int c = s >> 6;              // chunk 0..7
        const int l = s & 63;              // lane
        const int row = (c >> 1) * 16 + (l & 15);
        const int off = (c & 1) * 32 + ((l >> 4) * 8);
        const bf16x8 val = *(const bf16x8*)&Ls[row][off];
        *(bf16x8*)(dst + (size_t)s * 8) = val;
    }
}

// ---------------------------------------------------------------------------
// Main kernel — ZERO synchronization, register-pipelined (r17/r19 best:
// 41.75us, verified twice):
//  - 256 blocks x 512 thr (1 block/CU, 8 waves = 2/SIMD). Wave w<4 owns
//    32-row unit u = k4*4+w; wave w>=4 owns 63-u' -> same-SIMD pair (w,w+4)
//    has constant 33-tile total. No LDS, no barriers, free drift.
//  - even/odd register fragment buffers, each reloaded for tile t+2 right
//    after its last use -> every load covered by a full tile body (~600cy)
//    of independent work. Stalls decorrelate across free-running waves.
//  - r12 dual-subgroup compute (2:1 frag reuse), swapped QK + kperm V
//    (register P), fixed-max softmax, -MEXP in MFMA C-init.
// ---------------------------------------------------------------------------
__global__ __launch_bounds__(512, 2) void sdpa_fwd22(const float* __restrict__ Qg,
                                                     const short* __restrict__ wsK,
                                                     const short* __restrict__ wsV,
                                                     float* __restrict__ Og)
{
    // ---- block -> (head, k4); wave -> unit u ----
    const int b  = blockIdx.x;                 // 0..255
    const int x  = b & 7;                      // XCD
    const int head = x + 8 * ((b >> 3) & 3);   // 4 heads per XCD
    const int k4 = b >> 5;                     // 0..7

    const int tid  = threadIdx.x;
    const int wave = tid >> 6;                 // 0..7
    const int lane = tid & 63;
    const int lg   = lane >> 4;
    const int lc   = lane & 15;

    const int ulow = k4 * 4 + (wave & 3);
    const int u    = (wave < 4) ? ulow : (63 - ulow);   // 32-row unit 0..63

    const int q0 = u * 32;
    const int nt = (u >> 1) + 1;               // k-tiles for this unit
    const size_t hbase = (size_t)head * SEQ * DH;

    const char* gK = (const char*)(wsK + (size_t)head * NKT * TILE_SHORTS);
    const char* gV = (const char*)(wsV + (size_t)head * NKT * TILE_SHORTS);
    const int lb = lane * 16;
    const float QSCALE = 0.125f * 1.44269504f;
    const f32x4 minit = (f32x4){-MEXP, -MEXP, -MEXP, -MEXP};

    // ---- Q fragments for both 16-row subgroups ----
    bf16x8 qfA[2], qfB[2];
    #pragma unroll
    for (int gg = 0; gg < 2; ++gg) {
        const int qrow = q0 + gg * 16 + lc;
        #pragma unroll
        for (int d0 = 0; d0 < 2; ++d0) {
            const float* src = Qg + hbase + (size_t)qrow * DH + d0 * 32 + lg * 8;
            const float4 va = ((const float4*)src)[0];
            const float4 vb = ((const float4*)src)[1];
            bf16x8 f;
            f[0]=f2bf(va.x*QSCALE); f[1]=f2bf(va.y*QSCALE);
            f[2]=f2bf(va.z*QSCALE); f[3]=f2bf(va.w*QSCALE);
            f[4]=f2bf(vb.x*QSCALE); f[5]=f2bf(vb.y*QSCALE);
            f[6]=f2bf(vb.z*QSCALE); f[7]=f2bf(vb.w*QSCALE);
            if (gg == 0) qfA[d0] = f; else qfB[d0] = f;
        }
    }

    f32x4 oA[4], oB[4];
    #pragma unroll
    for (int dt = 0; dt < 4; ++dt) {
        oA[dt] = (f32x4){0.f, 0.f, 0.f, 0.f};
        oB[dt] = (f32x4){0.f, 0.f, 0.f, 0.f};
    }
    float lA = 0.f, lB = 0.f;

    bf16x8 kfE[8], vfE[8], kfO[8], vfO[8];

    auto loadT = [&](int t, bf16x8* kf, bf16x8* vf) {
        const char* bK = gK + (size_t)t * TILE_BYTES;
        const char* bV = gV + (size_t)t * TILE_BYTES;
        #pragma unroll
        for (int c = 0; c < 8; ++c) kf[c] = *(const bf16x8*)(bK + c * 1024 + lb);
        #pragma unroll
        for (int c = 0; c < 8; ++c) vf[c] = *(const bf16x8*)(bV + c * 1024 + lb);
    };

    auto body = [&](int t, const bf16x8* kf, const bf16x8* vf) {
        // ---- S^T = K Q^T, one K-frag feeds both subgroups ----
        f32x4 sA[4], sB[4];
        __builtin_amdgcn_s_setprio(1);
        #pragma unroll
        for (int n = 0; n < 4; ++n) {
            f32x4 aA = minit, aB = minit;
            #pragma unroll
            for (int d0 = 0; d0 < 2; ++d0) {
                const bf16x8 kfrag = kf[n*2 + d0];
                aA = __builtin_amdgcn_mfma_f32_16x16x32_bf16(kfrag, qfA[d0], aA, 0, 0, 0);
                aB = __builtin_amdgcn_mfma_f32_16x16x32_bf16(kfrag, qfB[d0], aB, 0, 0, 0);
            }
            sA[n] = aA; sB[n] = aB;
        }
        __builtin_amdgcn_s_setprio(0);

        // ---- causal mask (swapped indices), last tile only ----
        if (t == nt - 1) {
            const int qgA = q0 + lc;
            const int qgB = qgA + 16;
            #pragma unroll
            for (int n = 0; n < 4; ++n) {
                #pragma unroll
                for (int i = 0; i < 4; ++i) {
                    const int kg = t * KBLK + n*16 + lg*4 + i;
                    if (kg > qgA) sA[n][i] = -1e30f;
                    if (kg > qgB) sB[n][i] = -1e30f;
                }
            }
        }

        // ---- fixed-max softmax: P = 2^s ----
        #pragma unroll
        for (int n = 0; n < 4; ++n) {
            #pragma unroll
            for (int i = 0; i < 4; ++i) {
                const float pA = exp2fast(sA[n][i]);
                sA[n][i] = pA; lA += pA;
                const float pB = exp2fast(sB[n][i]);
                sB[n][i] = pB; lB += pB;
            }
        }

        // ---- pack P in-register ----
        bf16x8 paA0, paA1, paB0, paB1;
        #pragma unroll
        for (int i = 0; i < 4; ++i) {
            paA0[i]     = f2bf_hw(sA[0][i]);
            paA0[4 + i] = f2bf_hw(sA[1][i]);
            paA1[i]     = f2bf_hw(sA[2][i]);
            paA1[4 + i] = f2bf_hw(sA[3][i]);
            paB0[i]     = f2bf_hw(sB[0][i]);
            paB0[4 + i] = f2bf_hw(sB[1][i]);
            paB1[i]     = f2bf_hw(sB[2][i]);
            paB1[4 + i] = f2bf_hw(sB[3][i]);
        }

        // ---- O += P V, one V-frag feeds both subgroups ----
        __builtin_amdgcn_s_setprio(1);
        #pragma unroll
        for (int dt = 0; dt < 4; ++dt) {
            const bf16x8 vf0 = vf[dt*2 + 0];
            oA[dt] = __builtin_amdgcn_mfma_f32_16x16x32_bf16(paA0, vf0, oA[dt], 0, 0, 0);
            oB[dt] = __builtin_amdgcn_mfma_f32_16x16x32_bf16(paB0, vf0, oB[dt], 0, 0, 0);
        }
        #pragma unroll
        for (int dt = 0; dt < 4; ++dt) {
            const bf16x8 vf1 = vf[dt*2 + 1];
            oA[dt] = __builtin_amdgcn_mfma_f32_16x16x32_bf16(paA1, vf1, oA[dt], 0, 0, 0);
            oB[dt] = __builtin_amdgcn_mfma_f32_16x16x32_bf16(paB1, vf1, oB[dt], 0, 0, 0);
        }
        __builtin_amdgcn_s_setprio(0);
    };

    // ---- register-pipelined main loop: even/odd buffers, reload after use ----
    loadT(0, kfE, vfE);
    if (nt > 1) loadT(1, kfO, vfO);
    for (int tt = 0; tt < nt; tt += 2) {
        body(tt, kfE, vfE);
        if (tt + 2 < nt) loadT(tt + 2, kfE, vfE);   // covered by odd body
        if (tt + 1 < nt) {
            body(tt + 1, kfO, vfO);
            if (tt + 3 < nt) loadT(tt + 3, kfO, vfO);  // covered by next even body
        }
    }

    // ---- epilogue: per subgroup, reduce l across lg, shfl-transpose, store ----
    #pragma unroll
    for (int gg = 0; gg < 2; ++gg) {
        float l = (gg == 0) ? lA : lB;
        l += __shfl_xor(l, 16);
        l += __shfl_xor(l, 32);
        const float inv = 1.f / l;
        #pragma unroll
        for (int i = 0; i < 4; ++i) {
            const int q = lg*4 + i;
            const float invq = __shfl(inv, (lane & 48) | q);
            const int qg = q0 + gg*16 + q;
            float* dst = Og + hbase + (size_t)qg * DH;
            #pragma unroll
            for (int dt = 0; dt < 4; ++dt)
                dst[dt*16 + lc] = ((gg == 0) ? oA[dt][i] : oB[dt][i]) * invq;
        }
    }
}

// ---------------------------------------------------------------------------
// Fallback (round-1 kernel) if workspace is too small.
// ---------------------------------------------------------------------------
__global__ __launch_bounds__(256) void sdpa_fwd_fb(const float* __restrict__ Qg,
                                                   const float* __restrict__ Kg,
                                                   const float* __restrict__ Vg,
                                                   float* __restrict__ Og)
{
    __shared__ __align__(16) short Kt[KBLK][LDP];
    __shared__ __align__(16) short Vt[DH][LDP];
    __shared__ __align__(16) short Pt[4][16][LDP];

    const int head = blockIdx.y;
    const int qb   = 31 - blockIdx.x;
    const int tid  = threadIdx.x;
    const int wave = tid >> 6;
    const int lane = tid & 63;
    const int lg   = lane >> 4;
    const int lc   = lane & 15;

    const int q0 = qb * 64;
    const size_t hbase = (size_t)head * SEQ * DH;

    bf16x8 qfrag[2];
    {
        const int qrow = q0 + wave * 16 + lc;
        #pragma unroll
        for (int d0 = 0; d0 < 2; ++d0) {
            const float* src = Qg + hbase + (size_t)qrow * DH + d0 * 32 + lg * 8;
            const float4 va = ((const float4*)src)[0];
            const float4 vb = ((const float4*)src)[1];
            bf16x8 f;
            f[0]=f2bf(va.x*0.125f); f[1]=f2bf(va.y*0.125f);
            f[2]=f2bf(va.z*0.125f); f[3]=f2bf(va.w*0.125f);
            f[4]=f2bf(vb.x*0.125f); f[5]=f2bf(vb.y*0.125f);
            f[6]=f2bf(vb.z*0.125f); f[7]=f2bf(vb.w*0.125f);
            qfrag[d0] = f;
        }
    }

    f32x4 o_acc[4];
    #pragma unroll
    for (int dt = 0; dt < 4; ++dt) o_acc[dt] = (f32x4){0.f, 0.f, 0.f, 0.f};
    float m_run[4], l_run[4];
    #pragma unroll
    for (int i = 0; i < 4; ++i) { m_run[i] = -1e30f; l_run[i] = 0.f; }

    const int ntiles = qb + 1;
    for (int kt = 0; kt < ntiles; ++kt) {
        const int k0 = kt * KBLK;
        __syncthreads();
        #pragma unroll
        for (int it = 0; it < 4; ++it) {
            const int f  = tid + it * 256;
            const int kr = f >> 4;
            const int c4 = (f & 15) * 4;
            const float4 kv = *(const float4*)(Kg + hbase + (size_t)(k0 + kr) * DH + c4);
            short* kd = &Kt[kr][c4];
            kd[0]=f2bf(kv.x); kd[1]=f2bf(kv.y); kd[2]=f2bf(kv.z); kd[3]=f2bf(kv.w);
            const float4 vv = *(const float4*)(Vg + hbase + (size_t)(k0 + kr) * DH + c4);
            Vt[c4+0][kr]=f2bf(vv.x); Vt[c4+1][kr]=f2bf(vv.y);
            Vt[c4+2][kr]=f2bf(vv.z); Vt[c4+3][kr]=f2bf(vv.w);
        }
        __syncthreads();

        f32x4 s_acc[4];
        #pragma unroll
        for (int n = 0; n < 4; ++n) {
            f32x4 acc = {0.f, 0.f, 0.f, 0.f};
            #pragma unroll
            for (int d0 = 0; d0 < 2; ++d0) {
                const bf16x8 bfrag = *(const bf16x8*)&Kt[n*16 + lc][d0*32 + lg*8];
                acc = __builtin_amdgcn_mfma_f32_16x16x32_bf16(qfrag[d0], bfrag, acc, 0, 0, 0);
            }
            s_acc[n] = acc;
        }

        const int qrow_g = q0 + wave * 16 + lg * 4;
        if (kt == ntiles - 1) {
            #pragma unroll
            for (int i = 0; i < 4; ++i) {
                const int qg = qrow_g + i;
                #pragma unroll
                for (int n = 0; n < 4; ++n) {
                    const int kg = k0 + n*16 + lc;
                    if (kg > qg) s_acc[n][i] = -1e30f;
                }
            }
        }

        #pragma unroll
        for (int i = 0; i < 4; ++i) {
            float mx = fmaxf(fmaxf(s_acc[0][i], s_acc[1][i]),
                             fmaxf(s_acc[2][i], s_acc[3][i]));
            mx = fmaxf(mx, __shfl_xor(mx, 1));
            mx = fmaxf(mx, __shfl_xor(mx, 2));
            mx = fmaxf(mx, __shfl_xor(mx, 4));
            mx = fmaxf(mx, __shfl_xor(mx, 8));
            const float m_new = fmaxf(m_run[i], mx);
            const float corr = __expf(m_run[i] - m_new);
            m_run[i] = m_new;
            float rs = 0.f;
            #pragma unroll
            for (int n = 0; n < 4; ++n) {
                const float pp = __expf(s_acc[n][i] - m_new);
                s_acc[n][i] = pp;
                rs += pp;
            }
            rs += __shfl_xor(rs, 1);
            rs += __shfl_xor(rs, 2);
            rs += __shfl_xor(rs, 4);
            rs += __shfl_xor(rs, 8);
            l_run[i] = l_run[i] * corr + rs;
            #pragma unroll
            for (int dt = 0; dt < 4; ++dt) o_acc[dt][i] *= corr;
        }

        #pragma unroll
        for (int n = 0; n < 4; ++n) {
            #pragma unroll
            for (int i = 0; i < 4; ++i)
                Pt[wave][lg*4 + i][n*16 + lc] = f2bf(s_acc[n][i]);
        }
        asm volatile("s_waitcnt lgkmcnt(0)" ::: "memory");

        #pragma unroll
        for (int ks = 0; ks < 2; ++ks) {
            const bf16x8 afrag = *(const bf16x8*)&Pt[wave][lc][ks*32 + lg*8];
            #pragma unroll
            for (int dt = 0; dt < 4; ++dt) {
                const bf16x8 bfrag = *(const bf16x8*)&Vt[dt*16 + lc][ks*32 + lg*8];
                o_acc[dt] = __builtin_amdgcn_mfma_f32_16x16x32_bf16(afrag, bfrag, o_acc[dt], 0, 0, 0);
            }
        }
    }

    #pragma unroll
    for (int i = 0; i < 4; ++i) {
        const float inv = 1.f / l_run[i];
        const int qg = q0 + wave*16 + lg*4 + i;
        float* dst = Og + hbase + (size_t)qg * DH;
        #pragma unroll
        for (int dt = 0; dt < 4; ++dt)
            dst[dt*16 + lc] = o_acc[dt][i] * inv;
    }
}

extern "C" void kernel_launch(void* const* d_in, const int* in_sizes, int n_in,
                              void* d_out, int out_size, void* d_ws, size_t ws_size,
                              hipStream_t stream) {
    const float* Q = (const float*)d_in[0];
    const float* K = (const float*)d_in[1];
    const float* V = (const float*)d_in[2];
    float* O = (float*)d_out;
    const size_t need = (size_t)2 * NHEAD * SEQ * DH * sizeof(short);  // 16 MB
    if (ws_size >= need) {
        short* wsK = (short*)d_ws;
        short* wsV = wsK + (size_t)NHEAD * SEQ * DH;
        prep_kv<<<dim3(NKT, NHEAD, 2), 256, 0, stream>>>(K, V, wsK, wsV);
        sdpa_fwd22<<<dim3(256), 512, 0, stream>>>(Q, wsK, wsV, O);
    } else {
        sdpa_fwd_fb<<<dim3(32, NHEAD), 256, 0, stream>>>(Q, K, V, O);
    }
}